// Round 1
// baseline (847.933 us; speedup 1.0000x reference)
//
#include <hip/hip_runtime.h>
#include <cstdint>
#include <cstddef>

// ---------------------------------------------------------------------------
// Faster-RCNN-ish pipeline, MI355X (gfx950), fp32 baseline.
// Stages: conv1(3->64,s2) conv2(64->128,s2) conv3(128->256,s2) conv4(256->256,s2)
//         cls 1x1 -> softmax fg prob -> exact top-300 (bitonic, tie = low idx)
//         proposals for selected -> ROI max pool 3x3 (2x2 samples) ->
//         fc2(2304->256)+relu -> sigmoid cls head (20) + bbox head (4)
// fc1 is dead code in the reference (never used) -> skipped.
// ---------------------------------------------------------------------------

constexpr int ilog2c(int v) { int r = 0; while (v > 1) { v >>= 1; ++r; } return r; }

// ---------------- conv1: 3->64 stride2, 512->256, relu ----------------
__global__ __launch_bounds__(256)
void conv1_kernel(const float* __restrict__ x, const float* __restrict__ w,
                  const float* __restrict__ bias, float* __restrict__ out)
{
    const int co  = threadIdx.x;                    // 0..63
    const int pix = blockIdx.x * 4 + threadIdx.y;   // 0..4*256*256-1
    const int ox = pix & 255;
    const int oy = (pix >> 8) & 255;
    const int b  = pix >> 16;
    float acc = bias[co];
    #pragma unroll
    for (int ky = 0; ky < 3; ++ky) {
        const int iy = 2 * oy + ky;
        if (iy >= 512) continue;
        #pragma unroll
        for (int kx = 0; kx < 3; ++kx) {
            const int ix = 2 * ox + kx;
            if (ix >= 512) continue;
            const float* xp = x + ((size_t)((b * 512 + iy) * 512 + ix)) * 3;
            const float* wp = w + ((ky * 3 + kx) * 3) * 64 + co;
            acc = fmaf(xp[0], wp[0],   acc);
            acc = fmaf(xp[1], wp[64],  acc);
            acc = fmaf(xp[2], wp[128], acc);
        }
    }
    out[(size_t)pix * 64 + co] = fmaxf(acc, 0.f);
}

// ---------------- implicit-GEMM conv: 3x3 stride2, SAME(pad 0 before,1 after)
// out[m][n] = relu(bias[n] + sum_k patch[m][k] * w[k][n]),
// m = (b,oy,ox), k = (ky,kx,ci), w is HWIO flat = [9*CIN][COUT].
template<int CIN, int COUT, int HIN, int HOUT>
__global__ __launch_bounds__(256)
void conv_gemm(const float* __restrict__ in, const float* __restrict__ w,
               const float* __restrict__ bias, float* __restrict__ out)
{
    constexpr int K = 9 * CIN;
    constexpr int L2CIN  = ilog2c(CIN);
    constexpr int L2HOUT = ilog2c(HOUT);
    __shared__ float As[64][68];   // [k][m]
    __shared__ float Bs[64][68];   // [k][n]

    const int m0 = blockIdx.x * 64;
    const int n0 = blockIdx.y * 64;
    const int tid = threadIdx.x;
    const int tx = tid & 15, ty = tid >> 4;
    const int q     = tid & 15;   // float4 slot
    const int row16 = tid >> 4;   // 0..15

    float acc[4][4] = {};

    for (int k0 = 0; k0 < K; k0 += 64) {
        // ---- A tile: 64 pixels x 64 k  (global coalesced along ci) ----
        {
            const int kabs = k0 + q * 4;
            const int ci  = kabs & (CIN - 1);
            const int kxy = kabs >> L2CIN;     // 0..8, constant within this 64-slice
            const int ky = kxy / 3, kx = kxy - 3 * ky;
            #pragma unroll
            for (int r = 0; r < 4; ++r) {
                const int mm = row16 + 16 * r;
                const int m  = m0 + mm;
                const int ox = m & (HOUT - 1);
                const int oy = (m >> L2HOUT) & (HOUT - 1);
                const int bb = m >> (2 * L2HOUT);
                const int iy = 2 * oy + ky, ix = 2 * ox + kx;
                float4 v = make_float4(0.f, 0.f, 0.f, 0.f);
                if (iy < HIN && ix < HIN) {
                    v = *reinterpret_cast<const float4*>(
                        in + ((size_t)((bb * HIN + iy) * HIN + ix)) * CIN + ci);
                }
                As[q * 4 + 0][mm] = v.x;
                As[q * 4 + 1][mm] = v.y;
                As[q * 4 + 2][mm] = v.z;
                As[q * 4 + 3][mm] = v.w;
            }
        }
        // ---- B tile: 64 k x 64 n ----
        {
            #pragma unroll
            for (int r = 0; r < 4; ++r) {
                const int kk = row16 + 16 * r;
                float4 v = *reinterpret_cast<const float4*>(
                    w + (size_t)(k0 + kk) * COUT + n0 + q * 4);
                *reinterpret_cast<float4*>(&Bs[kk][q * 4]) = v;
            }
        }
        __syncthreads();
        #pragma unroll 8
        for (int kk = 0; kk < 64; ++kk) {
            const float4 a = *reinterpret_cast<const float4*>(&As[kk][ty * 4]);
            const float4 b = *reinterpret_cast<const float4*>(&Bs[kk][tx * 4]);
            const float av[4] = {a.x, a.y, a.z, a.w};
            const float bv[4] = {b.x, b.y, b.z, b.w};
            #pragma unroll
            for (int i = 0; i < 4; ++i)
                #pragma unroll
                for (int j = 0; j < 4; ++j)
                    acc[i][j] = fmaf(av[i], bv[j], acc[i][j]);
        }
        __syncthreads();
    }
    #pragma unroll
    for (int i = 0; i < 4; ++i) {
        const int m = m0 + ty * 4 + i;
        float4 o;
        o.x = fmaxf(acc[i][0] + bias[n0 + tx * 4 + 0], 0.f);
        o.y = fmaxf(acc[i][1] + bias[n0 + tx * 4 + 1], 0.f);
        o.z = fmaxf(acc[i][2] + bias[n0 + tx * 4 + 2], 0.f);
        o.w = fmaxf(acc[i][3] + bias[n0 + tx * 4 + 3], 0.f);
        *reinterpret_cast<float4*>(out + (size_t)m * COUT + n0 + tx * 4) = o;
    }
}

// ---------------- generic tiled GEMM for fc2: out = relu(A @ W + b) ----------
template<int K, int N>
__global__ __launch_bounds__(256)
void gemm_fc(const float* __restrict__ Aa, const float* __restrict__ w,
             const float* __restrict__ bias, float* __restrict__ out, int M)
{
    __shared__ float As[64][68];   // [k][m]
    __shared__ float Bs[64][68];   // [k][n]
    const int m0 = blockIdx.x * 64;
    const int n0 = blockIdx.y * 64;
    const int tid = threadIdx.x;
    const int tx = tid & 15, ty = tid >> 4;
    const int q = tid & 15, row16 = tid >> 4;
    float acc[4][4] = {};

    for (int k0 = 0; k0 < K; k0 += 64) {
        #pragma unroll
        for (int r = 0; r < 4; ++r) {
            const int mm = row16 + 16 * r;
            const int m  = m0 + mm;
            float4 v = make_float4(0.f, 0.f, 0.f, 0.f);
            if (m < M) {
                v = *reinterpret_cast<const float4*>(Aa + (size_t)m * K + k0 + q * 4);
            }
            As[q * 4 + 0][mm] = v.x;
            As[q * 4 + 1][mm] = v.y;
            As[q * 4 + 2][mm] = v.z;
            As[q * 4 + 3][mm] = v.w;
        }
        #pragma unroll
        for (int r = 0; r < 4; ++r) {
            const int kk = row16 + 16 * r;
            float4 v = *reinterpret_cast<const float4*>(
                w + (size_t)(k0 + kk) * N + n0 + q * 4);
            *reinterpret_cast<float4*>(&Bs[kk][q * 4]) = v;
        }
        __syncthreads();
        #pragma unroll 8
        for (int kk = 0; kk < 64; ++kk) {
            const float4 a = *reinterpret_cast<const float4*>(&As[kk][ty * 4]);
            const float4 b = *reinterpret_cast<const float4*>(&Bs[kk][tx * 4]);
            const float av[4] = {a.x, a.y, a.z, a.w};
            const float bv[4] = {b.x, b.y, b.z, b.w};
            #pragma unroll
            for (int i = 0; i < 4; ++i)
                #pragma unroll
                for (int j = 0; j < 4; ++j)
                    acc[i][j] = fmaf(av[i], bv[j], acc[i][j]);
        }
        __syncthreads();
    }
    #pragma unroll
    for (int i = 0; i < 4; ++i) {
        const int m = m0 + ty * 4 + i;
        if (m >= M) continue;
        float4 o;
        o.x = fmaxf(acc[i][0] + bias[n0 + tx * 4 + 0], 0.f);
        o.y = fmaxf(acc[i][1] + bias[n0 + tx * 4 + 1], 0.f);
        o.z = fmaxf(acc[i][2] + bias[n0 + tx * 4 + 2], 0.f);
        o.w = fmaxf(acc[i][3] + bias[n0 + tx * 4 + 3], 0.f);
        *reinterpret_cast<float4*>(out + (size_t)m * N + n0 + tx * 4) = o;
    }
}

// ---------------- cls 1x1 conv + softmax fg prob --------------------------
__global__ __launch_bounds__(256)
void clsprob_kernel(const float* __restrict__ f, const float* __restrict__ w_cls,
                    const float* __restrict__ b_cls, float* __restrict__ fg)
{
    const int t = blockIdx.x * 256 + threadIdx.x;   // 4*9216
    const int b = t / 9216;
    const int k = t - b * 9216;
    const int a = k % 9;
    const int pos = k / 9;
    const float* fv = f + (size_t)(b * 1024 + pos) * 256;
    float l0 = b_cls[2 * a], l1 = b_cls[2 * a + 1];
    #pragma unroll 4
    for (int ci = 0; ci < 256; ++ci) {
        const float xv = fv[ci];
        l0 = fmaf(xv, w_cls[ci * 18 + 2 * a],     l0);
        l1 = fmaf(xv, w_cls[ci * 18 + 2 * a + 1], l1);
    }
    const float m  = fmaxf(l0, l1);
    const float e0 = expf(l0 - m), e1 = expf(l1 - m);
    fg[t] = e1 / (e0 + e1);
}

// ---------------- exact top-300 per batch: bitonic sort of 16384 u64 -------
// key = (ordered_float(prob) << 32) | ~idx  -> descending sort gives
// values desc, ties by ascending index (matches jax.lax.top_k).
__global__ __launch_bounds__(1024)
void topk_kernel(const float* __restrict__ fg, int* __restrict__ top_idx,
                 float* __restrict__ out_prob)
{
    extern __shared__ unsigned long long keys[];
    const int b = blockIdx.x, tid = threadIdx.x;
    for (int i = tid; i < 16384; i += 1024) {
        unsigned long long kv = 0ull;
        if (i < 9216) {
            unsigned u = __float_as_uint(fg[b * 9216 + i]);
            u = (u & 0x80000000u) ? ~u : (u | 0x80000000u);
            kv = ((unsigned long long)u << 32) | (unsigned)(0xFFFFFFFFu - (unsigned)i);
        }
        keys[i] = kv;
    }
    __syncthreads();
    for (int k = 2; k <= 16384; k <<= 1) {
        for (int j = k >> 1; j > 0; j >>= 1) {
            for (int t = tid; t < 8192; t += 1024) {
                const int i = ((t & ~(j - 1)) << 1) | (t & (j - 1));
                const int p = i | j;
                const unsigned long long a = keys[i], c = keys[p];
                const bool desc = (i & k) == 0;
                if (desc ? (a < c) : (a > c)) { keys[i] = c; keys[p] = a; }
            }
            __syncthreads();
        }
    }
    if (tid < 300) {
        const unsigned long long kv = keys[tid];
        const unsigned u = (unsigned)(kv >> 32);
        const unsigned bits = (u & 0x80000000u) ? (u & 0x7FFFFFFFu) : ~u;
        out_prob[b * 300 + tid] = __uint_as_float(bits);
        top_idx[b * 300 + tid]  = (int)(0xFFFFFFFFu - (unsigned)(kv & 0xFFFFFFFFu));
    }
}

// ---------------- proposals for selected boxes (1 wave per item) -----------
__global__ __launch_bounds__(64)
void proposal_kernel(const float* __restrict__ f, const float* __restrict__ w_bbox,
                     const float* __restrict__ b_bbox, const int* __restrict__ top_idx,
                     float* __restrict__ out_prop, float* __restrict__ roib)
{
    const int item = blockIdx.x;          // 0..1199
    const int b = item / 300;
    const int idx = top_idx[item];
    const int a = idx % 9, pos = idx / 9;
    const int xw = pos & 31, yh = pos >> 5;
    const float* fv = f + ((size_t)((b * 32 + yh) * 32 + xw)) * 256;
    const int lane = threadIdx.x;
    const int j = lane & 3;
    float s = 0.f;
    for (int ci = lane >> 2; ci < 256; ci += 16)
        s = fmaf(fv[ci], w_bbox[ci * 36 + 4 * a + j], s);
    #pragma unroll
    for (int m = 4; m <= 32; m <<= 1) s += __shfl_xor(s, m, 64);
    const float d = s + b_bbox[4 * a + j];
    const float d0 = __shfl(d, 0, 64);
    const float d1 = __shfl(d, 1, 64);
    const float d2 = __shfl(d, 2, 64);
    const float d3 = __shfl(d, 3, 64);
    if (lane == 0) {
        const float anch_h[9] = {64, 64, 128, 128, 128, 256, 256, 256, 512};
        const float anch_w[9] = {64, 128, 64, 128, 256, 128, 256, 512, 256};
        const float cy = (yh + 0.5f) * 16.f, cx = (xw + 0.5f) * 16.f;
        const float ah = anch_h[a], aw = anch_w[a];
        const float yc = __fadd_rn(cy, __fmul_rn(d0, ah));
        const float xc = __fadd_rn(cx, __fmul_rn(d1, aw));
        const float hh = __fmul_rn(ah, expf(fminf(fmaxf(d2, -4.f), 4.f)));
        const float ww = __fmul_rn(aw, expf(fminf(fmaxf(d3, -4.f), 4.f)));
        const float y1 = fminf(fmaxf(__fsub_rn(yc, __fmul_rn(hh, 0.5f)), 0.f), 512.f);
        const float x1 = fminf(fmaxf(__fsub_rn(xc, __fmul_rn(ww, 0.5f)), 0.f), 512.f);
        const float y2 = fminf(fmaxf(__fadd_rn(yc, __fmul_rn(hh, 0.5f)), 0.f), 512.f);
        const float x2 = fminf(fmaxf(__fadd_rn(xc, __fmul_rn(ww, 0.5f)), 0.f), 512.f);
        float4 pr = make_float4(y1 * (1.f / 512.f), x1 * (1.f / 512.f),
                                y2 * (1.f / 512.f), x2 * (1.f / 512.f));
        *reinterpret_cast<float4*>(out_prop + (size_t)item * 4) = pr;
        // ROI-space boxes: normalized * 32 (exact power-of-two scalings)
        float4 rb = make_float4(pr.x * 32.f, pr.y * 32.f, pr.z * 32.f, pr.w * 32.f);
        *reinterpret_cast<float4*>(roib + (size_t)item * 4) = rb;
    }
}

// ---------------- ROI max pool 3x3, 2x2 samples per bin --------------------
__global__ __launch_bounds__(256)
void roi_pool_kernel(const float* __restrict__ f, const float* __restrict__ roib,
                     float* __restrict__ flat)
{
    const int item = blockIdx.x;   // 0..1199
    const int c = threadIdx.x;     // 0..255
    const int b = item / 300;
    const float ys0 = roib[item * 4 + 0], xs0 = roib[item * 4 + 1];
    const float ys1 = roib[item * 4 + 2], xs1 = roib[item * 4 + 3];
    const float bh = __fdiv_rn(__fsub_rn(ys1, ys0), 3.f);
    const float bw = __fdiv_rn(__fsub_rn(xs1, xs0), 3.f);
    int yi[3][2], xi[3][2];
    #pragma unroll
    for (int p = 0; p < 3; ++p) {
        #pragma unroll
        for (int s = 0; s < 2; ++s) {
            const float g = (float)p + (s ? 0.75f : 0.25f);
            const float ys = __fadd_rn(ys0, __fmul_rn(g, bh));
            const float xs = __fadd_rn(xs0, __fmul_rn(g, bw));
            yi[p][s] = (int)fminf(fmaxf(floorf(ys), 0.f), 31.f);
            xi[p][s] = (int)fminf(fmaxf(floorf(xs), 0.f), 31.f);
        }
    }
    const float* fb = f + (size_t)b * 32 * 32 * 256 + c;
    float* op = flat + (size_t)item * 2304 + c;
    #pragma unroll
    for (int py = 0; py < 3; ++py) {
        #pragma unroll
        for (int px = 0; px < 3; ++px) {
            const float v00 = fb[(size_t)(yi[py][0] * 32 + xi[px][0]) * 256];
            const float v01 = fb[(size_t)(yi[py][0] * 32 + xi[px][1]) * 256];
            const float v10 = fb[(size_t)(yi[py][1] * 32 + xi[px][0]) * 256];
            const float v11 = fb[(size_t)(yi[py][1] * 32 + xi[px][1]) * 256];
            op[(py * 3 + px) * 256] = fmaxf(fmaxf(v00, v01), fmaxf(v10, v11));
        }
    }
}

// ---------------- heads: sigmoid(fc2@Wc+bc), fc2@Wb+bb ---------------------
__global__ __launch_bounds__(256)
void heads_kernel(const float* __restrict__ fc2, const float* __restrict__ w_clsfc,
                  const float* __restrict__ b_clsfc, const float* __restrict__ w_bboxfc,
                  const float* __restrict__ b_bboxfc, float* __restrict__ out)
{
    const int t = blockIdx.x * 256 + threadIdx.x;
    if (t >= 1200 * 24) return;
    const int item = t / 24;
    const int j = t - item * 24;
    const float* v = fc2 + (size_t)item * 256;
    if (j < 20) {
        float s = b_clsfc[j];
        #pragma unroll 4
        for (int ci = 0; ci < 256; ++ci) s = fmaf(v[ci], w_clsfc[ci * 20 + j], s);
        out[6000 + item * 20 + j] = 1.f / (1.f + expf(-s));
    } else {
        const int q = j - 20;
        float s = b_bboxfc[q];
        #pragma unroll 4
        for (int ci = 0; ci < 256; ++ci) s = fmaf(v[ci], w_bboxfc[ci * 4 + q], s);
        out[30000 + item * 4 + q] = s;
    }
}

// ---------------------------------------------------------------------------
extern "C" void kernel_launch(void* const* d_in, const int* in_sizes, int n_in,
                              void* d_out, int out_size, void* d_ws, size_t ws_size,
                              hipStream_t stream)
{
    const float* x       = (const float*)d_in[0];
    const float* w1      = (const float*)d_in[1];
    const float* b1      = (const float*)d_in[2];
    const float* w2      = (const float*)d_in[3];
    const float* b2      = (const float*)d_in[4];
    const float* w3      = (const float*)d_in[5];
    const float* b3      = (const float*)d_in[6];
    const float* w4      = (const float*)d_in[7];
    const float* b4      = (const float*)d_in[8];
    const float* w_cls   = (const float*)d_in[9];
    const float* b_cls   = (const float*)d_in[10];
    const float* w_bbox  = (const float*)d_in[11];
    const float* b_bbox  = (const float*)d_in[12];
    // d_in[13], d_in[14] = w_fc1, b_fc1  (dead code in reference)
    const float* w_fc2   = (const float*)d_in[15];
    const float* b_fc2   = (const float*)d_in[16];
    const float* w_clsfc = (const float*)d_in[17];
    const float* b_clsfc = (const float*)d_in[18];
    const float* w_bboxfc= (const float*)d_in[19];
    const float* b_bboxfc= (const float*)d_in[20];
    float* out = (float*)d_out;
    char* ws = (char*)d_ws;

    // ws layout (with reuse):
    //   [0, 64MiB)        f1 (4,256,256,64)   -> later f3, then flat/fc2o
    //   [64MiB, +32MiB)   f2 (4,128,128,128)  -> later f4
    //   [96MiB, ...)      fg, top_idx, roib
    float* f1   = (float*)(ws + 0);
    float* f2   = (float*)(ws + 67108864);
    float* f3   = (float*)(ws + 0);
    float* f4   = (float*)(ws + 67108864);
    float* flat = (float*)(ws + 0);
    float* fc2o = (float*)(ws + 11059200);
    float* fg   = (float*)(ws + 100663296);
    int*   tidx = (int*)  (ws + 100810752);
    float* roib = (float*)(ws + 100815552);

    // backbone
    conv1_kernel<<<65536, dim3(64, 4), 0, stream>>>(x, w1, b1, f1);
    conv_gemm<64, 128, 256, 128><<<dim3(1024, 2), 256, 0, stream>>>(f1, w2, b2, f2);
    conv_gemm<128, 256, 128, 64><<<dim3(256, 4), 256, 0, stream>>>(f2, w3, b3, f3);
    conv_gemm<256, 256, 64, 32><<<dim3(64, 4), 256, 0, stream>>>(f3, w4, b4, f4);

    // RPN scores + exact top-300
    clsprob_kernel<<<144, 256, 0, stream>>>(f4, w_cls, b_cls, fg);
    topk_kernel<<<4, 1024, 131072, stream>>>(fg, tidx, out + 4800);

    // proposals + ROI pooling
    proposal_kernel<<<1200, 64, 0, stream>>>(f4, w_bbox, b_bbox, tidx, out, roib);
    roi_pool_kernel<<<1200, 256, 0, stream>>>(f4, roib, flat);

    // detection head
    gemm_fc<2304, 256><<<dim3(19, 4), 256, 0, stream>>>(flat, w_fc2, b_fc2, fc2o, 1200);
    heads_kernel<<<113, 256, 0, stream>>>(fc2o, w_clsfc, b_clsfc, w_bboxfc, b_bboxfc, out);
}